// Round 10
// baseline (1233.729 us; speedup 1.0000x reference)
//
#include <hip/hip_runtime.h>
#include <math.h>

// N=16384, IN=512, HID=256, E=262144.
// Z = adj @ (X@W), both GEMMs via fp16 split-2 MFMA (a=a1+a2, b=b1+b2;
// products a1b1+a1b2+a2b1). LDS-free, barrier-free fragment-direct scheme
// (R7-R9). R10: TLP fix -- gemm_adj restructured to 8 independent waves x
// (64x32) strips, <=128 VGPR, 2 blocks/CU => 16 waves/CU (was 8). Same
// traffic (adj read once, 1.07 GB), double the latency-hiding contexts.

typedef _Float16 half8v __attribute__((ext_vector_type(8)));
typedef __fp16   fp16x2 __attribute__((ext_vector_type(2)));
typedef __attribute__((ext_vector_type(4))) float floatx4;

#define NM_ (16384L * 256L)

// ---- RNE split (prep kernels; exact residual in f32) ----
static __device__ __forceinline__ void split2_pair_f16(float x0, float x1,
                                                       unsigned& q1, unsigned& q2) {
  _Float16 h0 = (_Float16)x0, h1 = (_Float16)x1;
  float r0 = x0 - (float)h0, r1 = x1 - (float)h1;
  _Float16 g0 = (_Float16)r0, g1 = (_Float16)r1;
  q1 = ((unsigned)__builtin_bit_cast(unsigned short, h1) << 16) |
       __builtin_bit_cast(unsigned short, h0);
  q2 = ((unsigned)__builtin_bit_cast(unsigned short, g1) << 16) |
       __builtin_bit_cast(unsigned short, g0);
}

// ---- RTZ in-register split: 8 f32 -> (a0, a1) fp16 ----
static __device__ __forceinline__ void split8(const float* __restrict__ x,
                                              half8v& a0, half8v& a1) {
  union U { unsigned u[4]; half8v h; } u0, u1;
#pragma unroll
  for (int p = 0; p < 4; ++p) {
    fp16x2 h = __builtin_amdgcn_cvt_pkrtz(x[2 * p], x[2 * p + 1]);
    float r0 = x[2 * p]     - (float)h[0];   // exact
    float r1 = x[2 * p + 1] - (float)h[1];
    fp16x2 g = __builtin_amdgcn_cvt_pkrtz(r0, r1);
    u0.u[p] = __builtin_bit_cast(unsigned, h);
    u1.u[p] = __builtin_bit_cast(unsigned, g);
  }
  a0 = u0.h; a1 = u1.h;
}

// ---- W[512][256] -> fragment-ready split WT: [s][kt(16)][c(4)][n(256)][8] ----
__global__ __launch_bounds__(256)
void w_split(const float* __restrict__ W, unsigned short* __restrict__ WT)
{
  const int b  = blockIdx.x;          // 64 blocks
  const int kt = b >> 2, c = b & 3;
  const int n  = threadIdx.x;
  const int k0 = kt * 32 + c * 8;
  float x[8];
#pragma unroll
  for (int j = 0; j < 8; ++j) x[j] = W[(k0 + j) * 256 + n];
  unsigned q1[4], q2[4];
#pragma unroll
  for (int p = 0; p < 4; ++p)
    split2_pair_f16(x[2 * p], x[2 * p + 1], q1[p], q2[p]);
  const long o = ((long)(kt * 4 + c) * 256 + n) * 8;
  *(uint4*)&WT[o]          = make_uint4(q1[0], q1[1], q1[2], q1[3]);
  *(uint4*)&WT[o + 131072] = make_uint4(q2[0], q2[1], q2[2], q2[3]);
}

// ---- GEMM1: XW = X @ W, LDS-free fragment-direct, chunk-4 accS ----
__global__ __launch_bounds__(256, 2)
void gemm_xw(const float* __restrict__ X, const unsigned short* __restrict__ WT,
             float* __restrict__ XW)
{
  const int tid  = threadIdx.x;
  const int lane = tid & 63;
  const int w    = tid >> 6;
  const int wm = w >> 1, wn = w & 1;
  const long m0 = (long)(blockIdx.x >> 1) * 128;
  const long n0 = (long)(blockIdx.x & 1) * 128;
  const int fr = lane & 15, kc = lane >> 4;

  const unsigned short* Bq = WT + (long)kc * 2048 + ((long)n0 + wn * 64 + fr) * 8;

  const float* ap[4];
#pragma unroll
  for (int fm = 0; fm < 4; ++fm)
    ap[fm] = X + (m0 + wm * 64 + fm * 16 + fr) * 512L + kc * 8;

  floatx4 acc[4][4], accS[4][4];
#pragma unroll
  for (int i = 0; i < 4; ++i)
#pragma unroll
    for (int j = 0; j < 4; ++j) { acc[i][j] = (floatx4)0.f; accS[i][j] = (floatx4)0.f; }

  for (int t = 0; t < 16; ++t) {
    half8v bf0[4], bf1[4];
#pragma unroll
    for (int fn = 0; fn < 4; ++fn) {
      bf0[fn] = *(const half8v*)(Bq + (long)t * 8192 + fn * 128);
      bf1[fn] = *(const half8v*)(Bq + (long)t * 8192 + fn * 128 + 131072);
    }
#pragma unroll
    for (int fm = 0; fm < 4; ++fm) {
      float x[8];
      *(float4*)&x[0] = *(const float4*)(ap[fm] + t * 32);
      *(float4*)&x[4] = *(const float4*)(ap[fm] + t * 32 + 4);
      half8v a0, a1;
      split8(x, a0, a1);
#pragma unroll
      for (int fn = 0; fn < 4; ++fn) {
        floatx4 d = acc[fm][fn];
        d = __builtin_amdgcn_mfma_f32_16x16x32_f16(a0, bf0[fn], d, 0, 0, 0);
        d = __builtin_amdgcn_mfma_f32_16x16x32_f16(a0, bf1[fn], d, 0, 0, 0);
        d = __builtin_amdgcn_mfma_f32_16x16x32_f16(a1, bf0[fn], d, 0, 0, 0);
        acc[fm][fn] = d;
      }
    }
    if ((t & 3) == 3) {   // chunk-4 flush: shortens fp32 chain at large |acc|
#pragma unroll
      for (int i = 0; i < 4; ++i)
#pragma unroll
        for (int j = 0; j < 4; ++j) { accS[i][j] += acc[i][j]; acc[i][j] = (floatx4)0.f; }
    }
  }
#pragma unroll
  for (int fm = 0; fm < 4; ++fm)
#pragma unroll
    for (int fn = 0; fn < 4; ++fn) {
      const long col  = n0 + wn * 64 + fn * 16 + fr;
      const long rowb = m0 + wm * 64 + fm * 16 + kc * 4;
#pragma unroll
      for (int j = 0; j < 4; ++j)
        XW[(rowb + j) * 256 + col] = accS[fm][fn][j];
    }
}

// ---- transpose + split2 XW -> fragment-ready: [s][kt(512)][c(4)][n(256)][8] ----
__global__ __launch_bounds__(256)
void transpose_split(const float* __restrict__ XW,
                     unsigned short* __restrict__ X1,
                     unsigned short* __restrict__ X2)
{
  __shared__ float T[64][65];
  const int tid = threadIdx.x;
  const long kb = (long)blockIdx.x * 64;   // XW row (k) tile
  const long nb = (long)blockIdx.y * 64;   // XW col (n) tile

#pragma unroll
  for (int i = 0; i < 4; ++i) {
    int idx = tid + 256 * i;
    int r = idx >> 4, c4 = (idx & 15) * 4;
    float4 v = *(const float4*)&XW[(kb + r) * 256 + nb + c4];
    T[r][c4 + 0] = v.x; T[r][c4 + 1] = v.y; T[r][c4 + 2] = v.z; T[r][c4 + 3] = v.w;
  }
  __syncthreads();

#pragma unroll
  for (int i = 0; i < 2; ++i) {
    int idx = tid + 256 * i;
    int n = idx >> 3, kq = (idx & 7) * 8;
    float x[8];
#pragma unroll
    for (int j = 0; j < 8; ++j) x[j] = T[kq + j][n];
    unsigned q1[4], q2[4];
#pragma unroll
    for (int p = 0; p < 4; ++p)
      split2_pair_f16(x[2 * p], x[2 * p + 1], q1[p], q2[p]);
    const long gk = kb + kq;
    const long gt = gk >> 5;
    const int  c  = (int)((gk >> 3) & 3);
    const long o  = ((gt * 4 + c) * 256 + (nb + n)) * 8;
    *(uint4*)&X1[o] = make_uint4(q1[0], q1[1], q1[2], q1[3]);
    *(uint4*)&X2[o] = make_uint4(q2[0], q2[1], q2[2], q2[3]);
  }
}

// ---- GEMM2: Z-partials = adj @ XW. LDS-free, barrier-free, high-TLP. ----
// 512 thr = 8 independent waves, each owns a 64x32 strip (wm=0, wn=w).
// BM=64, BN=256, split-K=2 -> grid 512 = 2 blocks/CU = 16 waves/CU.
// acc 4x2 + accS 4x2 = 64 VGPR of accumulators; launch_bounds caps at 128.
__global__ __launch_bounds__(512, 4)
void gemm_adj(const float* __restrict__ A, const unsigned short* __restrict__ Bg,
              float* __restrict__ P0, float* __restrict__ P1)
{
  const int tid  = threadIdx.x;
  const int lane = tid & 63;
  const int w    = tid >> 6;          // 0..7 = n-strip
  const int bid = blockIdx.x;
  const long m0 = (long)(bid & 255) * 64;
  const int  z  = bid >> 8;
  float* __restrict__ Cp = z ? P1 : P0;
  const int fr = lane & 15, kc = lane >> 4;

  const unsigned short* Bq0 = Bg + (long)z * 2097152 + (long)kc * 2048 +
                              ((long)w * 32 + fr) * 8;
  const unsigned short* Bq1 = Bq0 + NM_;

  const float* ap[4];
#pragma unroll
  for (int fm = 0; fm < 4; ++fm)
    ap[fm] = A + (m0 + fm * 16 + fr) * 16384L + (long)z * 8192 + kc * 8;

  floatx4 acc[4][2], accS[4][2];
#pragma unroll
  for (int i = 0; i < 4; ++i)
#pragma unroll
    for (int j = 0; j < 2; ++j) { acc[i][j] = (floatx4)0.f; accS[i][j] = (floatx4)0.f; }

  float  ra[4][8];     // raw A(t) per fm
  half8v bf0[2], bf1[2];

  // prologue: tile 0
#pragma unroll
  for (int fm = 0; fm < 4; ++fm) {
    *(float4*)&ra[fm][0] = *(const float4*)(ap[fm]);
    *(float4*)&ra[fm][4] = *(const float4*)(ap[fm] + 4);
  }
#pragma unroll
  for (int fn = 0; fn < 2; ++fn) {
    bf0[fn] = *(const half8v*)(Bq0 + fn * 128);
    bf1[fn] = *(const half8v*)(Bq1 + fn * 128);
  }

  for (int t = 0; t < 256; ++t) {
    const long ko = (long)((t + 1) & 255) * 32;     // next-tile A offset (wraps)
    const long bo = (long)((t + 1) & 255) * 8192;   // next-tile B offset
#pragma unroll
    for (int fm = 0; fm < 4; ++fm) {
      half8v a0, a1;
      split8(ra[fm], a0, a1);
      // reload ra[fm] for t+1 (regs free after split; ~1 iter of cover)
      *(float4*)&ra[fm][0] = *(const float4*)(ap[fm] + ko);
      *(float4*)&ra[fm][4] = *(const float4*)(ap[fm] + ko + 4);
#pragma unroll
      for (int fn = 0; fn < 2; ++fn) {
        floatx4 d = acc[fm][fn];
        d = __builtin_amdgcn_mfma_f32_16x16x32_f16(a0, bf0[fn], d, 0, 0, 0);
        d = __builtin_amdgcn_mfma_f32_16x16x32_f16(a0, bf1[fn], d, 0, 0, 0);
        d = __builtin_amdgcn_mfma_f32_16x16x32_f16(a1, bf0[fn], d, 0, 0, 0);
        acc[fm][fn] = d;
      }
    }
#pragma unroll
    for (int fn = 0; fn < 2; ++fn) {
      bf0[fn] = *(const half8v*)(Bq0 + bo + fn * 128);
      bf1[fn] = *(const half8v*)(Bq1 + bo + fn * 128);
    }
    if ((t & 31) == 31) {   // chunked accumulation (numerics, as R4-R9)
#pragma unroll
      for (int i = 0; i < 4; ++i)
#pragma unroll
        for (int j = 0; j < 2; ++j) { accS[i][j] += acc[i][j]; acc[i][j] = (floatx4)0.f; }
    }
  }

  // epilogue: C/D layout col=lane&15, row=kc*4+j
#pragma unroll
  for (int fm = 0; fm < 4; ++fm)
#pragma unroll
    for (int fn = 0; fn < 2; ++fn) {
      const long col  = w * 32 + fn * 16 + fr;
      const long rowb = m0 + fm * 16 + kc * 4;
#pragma unroll
      for (int j = 0; j < 4; ++j)
        Cp[(rowb + j) * 256 + col] = accS[fm][fn][j];
    }
}

// ---------------- P1 += P0 ----------------
__global__ __launch_bounds__(256)
void reduce_add(const float* __restrict__ P0, float* __restrict__ P1, long n4)
{
  long i = (long)blockIdx.x * 256 + threadIdx.x;
  const long stride = (long)gridDim.x * 256;
  for (; i < n4; i += stride) {
    float4 a = ((const float4*)P0)[i];
    float4 b = ((const float4*)P1)[i];
    b.x += a.x; b.y += a.y; b.z += a.z; b.w += a.w;
    ((float4*)P1)[i] = b;
  }
}

// ---------------- edge scoring ----------------
__global__ __launch_bounds__(256)
void edge_score(const float* __restrict__ Z, const float* __restrict__ w2,
                const int* __restrict__ te, const int* __restrict__ fe,
                int E, float* __restrict__ out)
{
  const long gtid = (long)blockIdx.x * 256 + threadIdx.x;
  const long wid = gtid >> 6;
  const int lane = threadIdx.x & 63;
  if (wid >= 2L * E) return;
  const int* ep = (wid < E) ? (te + 2 * wid) : (fe + 2 * (wid - E));
  const int src = ep[0];
  const int dst = ep[1];
  const float4 a = ((const float4*)(Z + (long)src * 256))[lane];
  const float4 b = ((const float4*)(Z + (long)dst * 256))[lane];
  const float4 w = ((const float4*)w2)[lane];
  float s = a.x * b.x * w.x + a.y * b.y * w.y + a.z * b.z * w.z + a.w * b.w * w.w;
#pragma unroll
  for (int off = 32; off > 0; off >>= 1) s += __shfl_down(s, off);
  if (lane == 0) out[wid] = 1.0f / (1.0f + expf(-s));
}

extern "C" void kernel_launch(void* const* d_in, const int* in_sizes, int n_in,
                              void* d_out, int out_size, void* d_ws, size_t ws_size,
                              hipStream_t stream)
{
  const float* X   = (const float*)d_in[0];
  const float* adj = (const float*)d_in[1];
  const float* W   = (const float*)d_in[2];
  const float* W2  = (const float*)d_in[3];
  const int*   te  = (const int*)d_in[4];
  const int*   fe  = (const int*)d_in[5];

  const int E = in_sizes[4] / 2;

  float* ws = (float*)d_ws;
  float* P0 = ws;                      // also XW (dead before gemm_adj writes)
  float* P1 = ws + NM_;                // final Z
  unsigned short* X1 = (unsigned short*)(ws + 2 * NM_);
  unsigned short* X2 = X1 + NM_;
  unsigned short* WT = X2 + NM_;       // 2 x 512 x 256 shorts = 0.5 MB
  // total ws: 2*NM*4 + 2*NM*2 + 0.5MB ~ 50.9 MB

  dim3 b256(256);
  w_split<<<dim3(64), b256, 0, stream>>>(W, WT);
  gemm_xw<<<dim3(256), b256, 0, stream>>>(X, WT, P0);          // XW -> P0 space
  transpose_split<<<dim3(256, 4), b256, 0, stream>>>(P0, X1, X2);
  gemm_adj<<<dim3(512), dim3(512), 0, stream>>>(adj, X1, P0, P1);
  reduce_add<<<dim3(2048), b256, 0, stream>>>(P0, P1, NM_ / 4);
  const long nwaves = 2L * E;
  const int nblocks = (int)((nwaves + 3) / 4);
  edge_score<<<dim3(nblocks), b256, 0, stream>>>(P1, W2, te, fe, E, (float*)d_out);
}

// Round 11
// 919.399 us; speedup vs baseline: 1.3419x; 1.3419x over previous
//
#include <hip/hip_runtime.h>
#include <math.h>

// N=16384, IN=512, HID=256, E=262144.
// Z = adj @ (X@W), both GEMMs via fp16 split-2 MFMA (a=a1+a2, b=b1+b2;
// products a1b1+a1b2+a2b1). LDS-free, barrier-free fragment-direct scheme.
// R11: R9 shape (BM=128/BN=256/splitK=2, adj read once) + DISTANCE-2
// ping-pong prefetch for B (bA/bB) and A (ra reloaded 2 tiles ahead,
// split into a0/a1 before the MFMA block). Fixes R9's exposed B-load
// latency (loads were issued adjacent to their waitcnt+use).

typedef _Float16 half8v __attribute__((ext_vector_type(8)));
typedef __fp16   fp16x2 __attribute__((ext_vector_type(2)));
typedef __attribute__((ext_vector_type(4))) float floatx4;

#define NM_ (16384L * 256L)

// ---- RNE split (prep kernels; exact residual in f32) ----
static __device__ __forceinline__ void split2_pair_f16(float x0, float x1,
                                                       unsigned& q1, unsigned& q2) {
  _Float16 h0 = (_Float16)x0, h1 = (_Float16)x1;
  float r0 = x0 - (float)h0, r1 = x1 - (float)h1;
  _Float16 g0 = (_Float16)r0, g1 = (_Float16)r1;
  q1 = ((unsigned)__builtin_bit_cast(unsigned short, h1) << 16) |
       __builtin_bit_cast(unsigned short, h0);
  q2 = ((unsigned)__builtin_bit_cast(unsigned short, g1) << 16) |
       __builtin_bit_cast(unsigned short, g0);
}

// ---- RTZ in-register split: 8 f32 -> (a0, a1) fp16 ----
static __device__ __forceinline__ void split8(const float* __restrict__ x,
                                              half8v& a0, half8v& a1) {
  union U { unsigned u[4]; half8v h; } u0, u1;
#pragma unroll
  for (int p = 0; p < 4; ++p) {
    fp16x2 h = __builtin_amdgcn_cvt_pkrtz(x[2 * p], x[2 * p + 1]);
    float r0 = x[2 * p]     - (float)h[0];   // exact
    float r1 = x[2 * p + 1] - (float)h[1];
    fp16x2 g = __builtin_amdgcn_cvt_pkrtz(r0, r1);
    u0.u[p] = __builtin_bit_cast(unsigned, h);
    u1.u[p] = __builtin_bit_cast(unsigned, g);
  }
  a0 = u0.h; a1 = u1.h;
}

// ---- W[512][256] -> fragment-ready split WT: [s][kt(16)][c(4)][n(256)][8] ----
__global__ __launch_bounds__(256)
void w_split(const float* __restrict__ W, unsigned short* __restrict__ WT)
{
  const int b  = blockIdx.x;          // 64 blocks
  const int kt = b >> 2, c = b & 3;
  const int n  = threadIdx.x;
  const int k0 = kt * 32 + c * 8;
  float x[8];
#pragma unroll
  for (int j = 0; j < 8; ++j) x[j] = W[(k0 + j) * 256 + n];
  unsigned q1[4], q2[4];
#pragma unroll
  for (int p = 0; p < 4; ++p)
    split2_pair_f16(x[2 * p], x[2 * p + 1], q1[p], q2[p]);
  const long o = ((long)(kt * 4 + c) * 256 + n) * 8;
  *(uint4*)&WT[o]          = make_uint4(q1[0], q1[1], q1[2], q1[3]);
  *(uint4*)&WT[o + 131072] = make_uint4(q2[0], q2[1], q2[2], q2[3]);
}

// ---- GEMM1: XW = X @ W, LDS-free fragment-direct, chunk-4 accS ----
__global__ __launch_bounds__(256, 2)
void gemm_xw(const float* __restrict__ X, const unsigned short* __restrict__ WT,
             float* __restrict__ XW)
{
  const int tid  = threadIdx.x;
  const int lane = tid & 63;
  const int w    = tid >> 6;
  const int wm = w >> 1, wn = w & 1;
  const long m0 = (long)(blockIdx.x >> 1) * 128;
  const long n0 = (long)(blockIdx.x & 1) * 128;
  const int fr = lane & 15, kc = lane >> 4;

  const unsigned short* Bq = WT + (long)kc * 2048 + ((long)n0 + wn * 64 + fr) * 8;

  const float* ap[4];
#pragma unroll
  for (int fm = 0; fm < 4; ++fm)
    ap[fm] = X + (m0 + wm * 64 + fm * 16 + fr) * 512L + kc * 8;

  floatx4 acc[4][4], accS[4][4];
#pragma unroll
  for (int i = 0; i < 4; ++i)
#pragma unroll
    for (int j = 0; j < 4; ++j) { acc[i][j] = (floatx4)0.f; accS[i][j] = (floatx4)0.f; }

  for (int t = 0; t < 16; ++t) {
    half8v bf0[4], bf1[4];
#pragma unroll
    for (int fn = 0; fn < 4; ++fn) {
      bf0[fn] = *(const half8v*)(Bq + (long)t * 8192 + fn * 128);
      bf1[fn] = *(const half8v*)(Bq + (long)t * 8192 + fn * 128 + 131072);
    }
#pragma unroll
    for (int fm = 0; fm < 4; ++fm) {
      float x[8];
      *(float4*)&x[0] = *(const float4*)(ap[fm] + t * 32);
      *(float4*)&x[4] = *(const float4*)(ap[fm] + t * 32 + 4);
      half8v a0, a1;
      split8(x, a0, a1);
#pragma unroll
      for (int fn = 0; fn < 4; ++fn) {
        floatx4 d = acc[fm][fn];
        d = __builtin_amdgcn_mfma_f32_16x16x32_f16(a0, bf0[fn], d, 0, 0, 0);
        d = __builtin_amdgcn_mfma_f32_16x16x32_f16(a0, bf1[fn], d, 0, 0, 0);
        d = __builtin_amdgcn_mfma_f32_16x16x32_f16(a1, bf0[fn], d, 0, 0, 0);
        acc[fm][fn] = d;
      }
    }
    if ((t & 3) == 3) {   // chunk-4 flush: shortens fp32 chain at large |acc|
#pragma unroll
      for (int i = 0; i < 4; ++i)
#pragma unroll
        for (int j = 0; j < 4; ++j) { accS[i][j] += acc[i][j]; acc[i][j] = (floatx4)0.f; }
    }
  }
#pragma unroll
  for (int fm = 0; fm < 4; ++fm)
#pragma unroll
    for (int fn = 0; fn < 4; ++fn) {
      const long col  = n0 + wn * 64 + fn * 16 + fr;
      const long rowb = m0 + wm * 64 + fm * 16 + kc * 4;
#pragma unroll
      for (int j = 0; j < 4; ++j)
        XW[(rowb + j) * 256 + col] = accS[fm][fn][j];
    }
}

// ---- transpose + split2 XW -> fragment-ready: [s][kt(512)][c(4)][n(256)][8] ----
__global__ __launch_bounds__(256)
void transpose_split(const float* __restrict__ XW,
                     unsigned short* __restrict__ X1,
                     unsigned short* __restrict__ X2)
{
  __shared__ float T[64][65];
  const int tid = threadIdx.x;
  const long kb = (long)blockIdx.x * 64;   // XW row (k) tile
  const long nb = (long)blockIdx.y * 64;   // XW col (n) tile

#pragma unroll
  for (int i = 0; i < 4; ++i) {
    int idx = tid + 256 * i;
    int r = idx >> 4, c4 = (idx & 15) * 4;
    float4 v = *(const float4*)&XW[(kb + r) * 256 + nb + c4];
    T[r][c4 + 0] = v.x; T[r][c4 + 1] = v.y; T[r][c4 + 2] = v.z; T[r][c4 + 3] = v.w;
  }
  __syncthreads();

#pragma unroll
  for (int i = 0; i < 2; ++i) {
    int idx = tid + 256 * i;
    int n = idx >> 3, kq = (idx & 7) * 8;
    float x[8];
#pragma unroll
    for (int j = 0; j < 8; ++j) x[j] = T[kq + j][n];
    unsigned q1[4], q2[4];
#pragma unroll
    for (int p = 0; p < 4; ++p)
      split2_pair_f16(x[2 * p], x[2 * p + 1], q1[p], q2[p]);
    const long gk = kb + kq;
    const long gt = gk >> 5;
    const int  c  = (int)((gk >> 3) & 3);
    const long o  = ((gt * 4 + c) * 256 + (nb + n)) * 8;
    *(uint4*)&X1[o] = make_uint4(q1[0], q1[1], q1[2], q1[3]);
    *(uint4*)&X2[o] = make_uint4(q2[0], q2[1], q2[2], q2[3]);
  }
}

// ---- GEMM2: Z-partials = adj @ XW. LDS-free, barrier-free, dist-2 prefetch. ----
// 512 thr = 8 waves (2m x 4n), BM=128 BN=256, split-K=2 -> grid 256 (1/CU).
// Per iter: MFMA(tile t) -> split A(t+1) -> load A(t+2) -> load B(t+2).
// B ping-pong bA/bB gives one full iteration of load->use cover.
__global__ __launch_bounds__(512)
void gemm_adj(const float* __restrict__ A, const unsigned short* __restrict__ Bg,
              float* __restrict__ P0, float* __restrict__ P1)
{
  const int tid  = threadIdx.x;
  const int lane = tid & 63;
  const int w    = tid >> 6;          // 0..7
  const int wm = w >> 2, wn = w & 3;
  const int bid = blockIdx.x;
  const long m0 = (long)(bid & 127) * 128;
  const int  z  = bid >> 7;
  float* __restrict__ Cp = z ? P1 : P0;
  const int fr = lane & 15, kc = lane >> 4;

  const unsigned short* Bq0 = Bg + (long)z * 2097152 + (long)kc * 2048 +
                              ((long)wn * 64 + fr) * 8;
  const unsigned short* Bq1 = Bq0 + NM_;

  const float* ap[4];
#pragma unroll
  for (int fm = 0; fm < 4; ++fm)
    ap[fm] = A + (m0 + wm * 64 + fm * 16 + fr) * 16384L + (long)z * 8192 + kc * 8;

  floatx4 acc[4][4], accS[4][4];
#pragma unroll
  for (int i = 0; i < 4; ++i)
#pragma unroll
    for (int j = 0; j < 4; ++j) { acc[i][j] = (floatx4)0.f; accS[i][j] = (floatx4)0.f; }

  float  ra[4][8];            // raw A, 2 tiles ahead
  half8v a0[4], a1[4];        // split A for current tile
  half8v bA0[4], bA1[4];      // B for even tiles
  half8v bB0[4], bB1[4];      // B for odd tiles

#define LOADA(TILE)                                                               \
  {                                                                               \
    const long ko_ = (long)((TILE) & 255) * 32;                                   \
    _Pragma("unroll")                                                             \
    for (int fm = 0; fm < 4; ++fm) {                                              \
      *(float4*)&ra[fm][0] = *(const float4*)(ap[fm] + ko_);                      \
      *(float4*)&ra[fm][4] = *(const float4*)(ap[fm] + ko_ + 4);                  \
    }                                                                             \
  }

#define LOADB(D0, D1, TILE)                                                       \
  {                                                                               \
    const long bo_ = (long)((TILE) & 255) * 8192;                                 \
    _Pragma("unroll")                                                             \
    for (int fn = 0; fn < 4; ++fn) {                                              \
      D0[fn] = *(const half8v*)(Bq0 + bo_ + fn * 128);                            \
      D1[fn] = *(const half8v*)(Bq1 + bo_ + fn * 128);                            \
    }                                                                             \
  }

#define SPLITA                                                                    \
  {                                                                               \
    _Pragma("unroll")                                                             \
    for (int fm = 0; fm < 4; ++fm) split8(ra[fm], a0[fm], a1[fm]);                \
  }

#define MFMAS(B0, B1)                                                             \
  {                                                                               \
    _Pragma("unroll")                                                             \
    for (int fm = 0; fm < 4; ++fm)                                                \
      _Pragma("unroll")                                                           \
      for (int fn = 0; fn < 4; ++fn) {                                            \
        floatx4 d = acc[fm][fn];                                                  \
        d = __builtin_amdgcn_mfma_f32_16x16x32_f16(a0[fm], B0[fn], d, 0, 0, 0);   \
        d = __builtin_amdgcn_mfma_f32_16x16x32_f16(a0[fm], B1[fn], d, 0, 0, 0);   \
        d = __builtin_amdgcn_mfma_f32_16x16x32_f16(a1[fm], B0[fn], d, 0, 0, 0);   \
        acc[fm][fn] = d;                                                          \
      }                                                                           \
  }

#define FLUSH                                                                     \
  {                                                                               \
    _Pragma("unroll")                                                             \
    for (int i = 0; i < 4; ++i)                                                   \
      _Pragma("unroll")                                                           \
      for (int j = 0; j < 4; ++j) { accS[i][j] += acc[i][j]; acc[i][j] = (floatx4)0.f; } \
  }

  // prologue: ra<-A(0); bA<-B(0); bB<-B(1); a<-split(A0); ra<-A(1)
  LOADA(0);
  LOADB(bA0, bA1, 0);
  LOADB(bB0, bB1, 1);
  SPLITA;
  LOADA(1);

  for (int t = 0; t < 256; t += 2) {
    // even tile t: consume a(t), bA(t)
    MFMAS(bA0, bA1);
    SPLITA;               // a <- split(ra) = A(t+1)
    LOADA(t + 2);         // ra <- A(t+2)
    LOADB(bA0, bA1, t + 2);
    // odd tile t+1: consume a(t+1), bB(t+1)
    MFMAS(bB0, bB1);
    SPLITA;               // a <- A(t+2)
    LOADA(t + 3);
    LOADB(bB0, bB1, t + 3);
    if (((t + 1) & 31) == 31) FLUSH;   // every 32 tiles (numerics, as R4-R10)
  }

  // epilogue: C/D layout col=lane&15, row=kc*4+j
#pragma unroll
  for (int fm = 0; fm < 4; ++fm)
#pragma unroll
    for (int fn = 0; fn < 4; ++fn) {
      const long col  = wn * 64 + fn * 16 + fr;
      const long rowb = m0 + wm * 64 + fm * 16 + kc * 4;
#pragma unroll
      for (int j = 0; j < 4; ++j)
        Cp[(rowb + j) * 256 + col] = accS[fm][fn][j];
    }
#undef LOADA
#undef LOADB
#undef SPLITA
#undef MFMAS
#undef FLUSH
}

// ---------------- P1 += P0 ----------------
__global__ __launch_bounds__(256)
void reduce_add(const float* __restrict__ P0, float* __restrict__ P1, long n4)
{
  long i = (long)blockIdx.x * 256 + threadIdx.x;
  const long stride = (long)gridDim.x * 256;
  for (; i < n4; i += stride) {
    float4 a = ((const float4*)P0)[i];
    float4 b = ((const float4*)P1)[i];
    b.x += a.x; b.y += a.y; b.z += a.z; b.w += a.w;
    ((float4*)P1)[i] = b;
  }
}

// ---------------- edge scoring ----------------
__global__ __launch_bounds__(256)
void edge_score(const float* __restrict__ Z, const float* __restrict__ w2,
                const int* __restrict__ te, const int* __restrict__ fe,
                int E, float* __restrict__ out)
{
  const long gtid = (long)blockIdx.x * 256 + threadIdx.x;
  const long wid = gtid >> 6;
  const int lane = threadIdx.x & 63;
  if (wid >= 2L * E) return;
  const int* ep = (wid < E) ? (te + 2 * wid) : (fe + 2 * (wid - E));
  const int src = ep[0];
  const int dst = ep[1];
  const float4 a = ((const float4*)(Z + (long)src * 256))[lane];
  const float4 b = ((const float4*)(Z + (long)dst * 256))[lane];
  const float4 w = ((const float4*)w2)[lane];
  float s = a.x * b.x * w.x + a.y * b.y * w.y + a.z * b.z * w.z + a.w * b.w * w.w;
#pragma unroll
  for (int off = 32; off > 0; off >>= 1) s += __shfl_down(s, off);
  if (lane == 0) out[wid] = 1.0f / (1.0f + expf(-s));
}

extern "C" void kernel_launch(void* const* d_in, const int* in_sizes, int n_in,
                              void* d_out, int out_size, void* d_ws, size_t ws_size,
                              hipStream_t stream)
{
  const float* X   = (const float*)d_in[0];
  const float* adj = (const float*)d_in[1];
  const float* W   = (const float*)d_in[2];
  const float* W2  = (const float*)d_in[3];
  const int*   te  = (const int*)d_in[4];
  const int*   fe  = (const int*)d_in[5];

  const int E = in_sizes[4] / 2;

  float* ws = (float*)d_ws;
  float* P0 = ws;                      // also XW (dead before gemm_adj writes)
  float* P1 = ws + NM_;                // final Z
  unsigned short* X1 = (unsigned short*)(ws + 2 * NM_);
  unsigned short* X2 = X1 + NM_;
  unsigned short* WT = X2 + NM_;       // 2 x 512 x 256 shorts = 0.5 MB
  // total ws: 2*NM*4 + 2*NM*2 + 0.5MB ~ 50.9 MB

  dim3 b256(256);
  w_split<<<dim3(64), b256, 0, stream>>>(W, WT);
  gemm_xw<<<dim3(256), b256, 0, stream>>>(X, WT, P0);          // XW -> P0 space
  transpose_split<<<dim3(256, 4), b256, 0, stream>>>(P0, X1, X2);
  gemm_adj<<<dim3(256), dim3(512), 0, stream>>>(adj, X1, P0, P1);
  reduce_add<<<dim3(2048), b256, 0, stream>>>(P0, P1, NM_ / 4);
  const long nwaves = 2L * E;
  const int nblocks = (int)((nwaves + 3) / 4);
  edge_score<<<dim3(nblocks), b256, 0, stream>>>(P1, W2, te, fe, E, (float*)d_out);
}